// Round 6
// baseline (639.455 us; speedup 1.0000x reference)
//
#include <hip/hip_runtime.h>

typedef __bf16 bf8 __attribute__((ext_vector_type(8)));
typedef float f4 __attribute__((ext_vector_type(4)));
typedef unsigned short us4 __attribute__((ext_vector_type(4)));

#define MFMA16(a,b,c) __builtin_amdgcn_mfma_f32_16x16x32_bf16((a),(b),(c),0,0,0)

#define BLOCK 1024
#define NWAVE 16   // waves per block; LDS ~75.2 KB -> 2 blocks/CU -> 32 waves/CU

__device__ __forceinline__ unsigned short f2bfu(float f){
  __bf16 h = (__bf16)f;
  union { __bf16 b; unsigned short u; } v; v.b = h; return v.u;
}

// Wave-local LDS fence: stalls only THIS wave until its DS ops completed.
// Act buffers are wave-private, so this replaces __syncthreads() between
// layers (validated correct rounds 4-5, absmax 0.0).
__device__ __forceinline__ void wfence(){
  asm volatile("s_waitcnt lgkmcnt(0)" ::: "memory");
}

// LDS layout (ushort element offsets)
#define OFF_W1   0       // 32->64 : 1 kstep * 4 mtiles * 512 = 2048
#define OFF_W2   2048    // 64->64 : 2*4*512 = 4096
#define OFF_W3   6144    // 64->16 : 2*1*512 = 1024
#define OFF_CW1  7168    // 16->64 : 1*4*512 = 2048 (zero-padded K)
#define OFF_CW2  9216    // 64->64 : 4096
#define OFF_CW3  13312   // 64->64 : 4096
#define OFF_CW4  17408   // 64->3  : 2*1*512 = 1024 (zero-padded M)
#define OFF_ACT  18432
#define ACT_STRIDE 72    // 64 features + 8 pad
#define SMEM_US  (18432 + NWAVE*16*ACT_STRIDE)   // 73728 B

// bias offsets (floats)
#define BO_B1  0
#define BO_B2  64
#define BO_B3  128
#define BO_CB1 144
#define BO_CB2 208
#define BO_CB3 272
#define BO_CB4 336

// Stage weights from global (fin x fout row-major FP32) into LDS as bf16 in
// A-fragment order: element ((s*MT+t)*64+lane)*8+j holds w[k=s*32+(lane>>4)*8+j][o=t*16+(lane&15)].
template<int FIN,int FOUT,int KS,int MT>
__device__ __forceinline__ void stage_w(const float* w, unsigned short* dst){
  const int total = KS*MT*512;
  for (int e = threadIdx.x; e < total; e += BLOCK){
    int chunk = e >> 9;
    int s = chunk / MT, t = chunk % MT;
    int le = e & 511;
    int lane = le >> 3, j = le & 7;
    int q = lane >> 4, m = lane & 15;
    int i = s*32 + q*8 + j;
    int o = t*16 + m;
    dst[e] = (i < FIN && o < FOUT) ? f2bfu(w[i*FOUT + o]) : (unsigned short)0;
  }
}

// One 64->64 layer for one wave's 16-point tile, LDS act round-trip.
__device__ __forceinline__ void layer64(const unsigned short* wlds, const float* bias,
                                        unsigned short* act, int lane, bool relu){
  const int q = lane >> 4, m = lane & 15;
  bf8 b0 = *(const bf8*)(act + m*ACT_STRIDE + q*8);        // k = 0..31
  bf8 b1 = *(const bf8*)(act + m*ACT_STRIDE + 32 + q*8);   // k = 32..63
  f4 acc[4];
#pragma unroll
  for (int t = 0; t < 4; ++t){
    f4 c = {0.f,0.f,0.f,0.f};
    c = MFMA16(*(const bf8*)(wlds + ((0*4+t)*64+lane)*8), b0, c);
    c = MFMA16(*(const bf8*)(wlds + ((1*4+t)*64+lane)*8), b1, c);
    acc[t] = c;
  }
#pragma unroll
  for (int t = 0; t < 4; ++t){
    us4 pk;
#pragma unroll
    for (int r = 0; r < 4; ++r){
      float v = acc[t][r] + bias[t*16 + q*4 + r];
      if (relu) v = fmaxf(v, 0.f);
      pk[r] = f2bfu(v);
    }
    *(us4*)(act + m*ACT_STRIDE + t*16 + q*4) = pk;
  }
}

__global__ __launch_bounds__(BLOCK, 8) void nerf_fused(
    const float* __restrict__ xin, const float* __restrict__ tab,
    const float* __restrict__ w1,  const float* __restrict__ b1,
    const float* __restrict__ w2,  const float* __restrict__ b2,
    const float* __restrict__ w3,  const float* __restrict__ b3,
    const float* __restrict__ cw1, const float* __restrict__ cb1,
    const float* __restrict__ cw2, const float* __restrict__ cb2,
    const float* __restrict__ cw3, const float* __restrict__ cb3,
    const float* __restrict__ cw4, const float* __restrict__ cb4,
    float* __restrict__ out, int nB)
{
  __shared__ __align__(16) unsigned short smem[SMEM_US];
  __shared__ __align__(16) float sbias[340];
  __shared__ int sres[16];

  stage_w<32,64,1,4>(w1,  smem+OFF_W1);
  stage_w<64,64,2,4>(w2,  smem+OFF_W2);
  stage_w<64,16,2,1>(w3,  smem+OFF_W3);
  stage_w<16,64,1,4>(cw1, smem+OFF_CW1);
  stage_w<64,64,2,4>(cw2, smem+OFF_CW2);
  stage_w<64,64,2,4>(cw3, smem+OFF_CW3);
  stage_w<64, 3,2,1>(cw4, smem+OFF_CW4);
  {
    int t = threadIdx.x;
    if (t < 64){
      sbias[BO_B1 +t] = b1[t];
      sbias[BO_B2 +t] = b2[t];
      sbias[BO_CB1+t] = cb1[t];
      sbias[BO_CB2+t] = cb2[t];
      sbias[BO_CB3+t] = cb3[t];
    }
    if (t < 16) sbias[BO_B3+t] = b3[t];
    if (t < 3)  sbias[BO_CB4+t] = cb4[t];
    if (t < 16){
      const int RES_[16] = {16,20,25,32,40,50,64,80,101,128,161,203,256,322,406,512};
      sres[t] = RES_[t];
    }
  }
  __syncthreads();   // weights/bias staging -> everything (only block barrier)

  const int lane = threadIdx.x & 63, wv = threadIdx.x >> 6;
  const int q = lane >> 4, m = lane & 15;
  unsigned short* act = smem + OFF_ACT + wv*16*ACT_STRIDE;

  int res_[4];
#pragma unroll
  for (int d = 0; d < 4; ++d) res_[d] = sres[4*q + d];

  for (int it = 0; it < 4; ++it){
    const int gp  = blockIdx.x*BLOCK + wv*64 + it*16 + m;  // block covers 1024 points
    const int gpl = min(gp, nB-1);
    const float px = xin[gpl*3+0];
    const float py = xin[gpl*3+1];
    const float pz = xin[gpl*3+2];

    // ---- hash encode: this lane's 8 features ARE its layer-1 B-fragment ----
    bf8 bfrag;
#pragma unroll
    for (int d = 0; d < 4; ++d){
      const int lvl = 4*q + d;
      const int res = res_[d];
      const float sc = 0.5f*(float)(res-1);
      const float xs=(px+1.f)*sc, ys=(py+1.f)*sc, zs=(pz+1.f)*sc;
      const float fx=floorf(xs), fy=floorf(ys), fz=floorf(zs);
      const float wx=xs-fx, wy=ys-fy, wz=zs-fz;
      int ix0=min(max((int)fx,0),res-1);
      int iy0=min(max((int)fy,0),res-1);
      int iz0=min(max((int)fz,0),res-1);
      int ix1=min(ix0+1,res-1), iy1=min(iy0+1,res-1), iz1=min(iz0+1,res-1);
      const bool dense = (lvl < 3);   // 16^3,20^3,25^3 <= 16384
      unsigned X0,X1,Y0,Y1,Z0,Z1;
      if (dense){
        X0=(unsigned)ix0;            X1=(unsigned)ix1;
        Y0=(unsigned)(res*iy0);      Y1=(unsigned)(res*iy1);
        Z0=(unsigned)(res*res*iz0);  Z1=(unsigned)(res*res*iz1);
      } else {
        X0=(unsigned)ix0;                 X1=(unsigned)ix1;
        Y0=(unsigned)iy0*2654435761u;     Y1=(unsigned)iy1*2654435761u;
        Z0=(unsigned)iz0*805459861u;      Z1=(unsigned)iz1*805459861u;
      }
      const float wx0=1.f-wx, wy0=1.f-wy, wz0=1.f-wz;
      float f0=0.f, f1=0.f;
      const float2* tl = (const float2*)tab + (lvl<<14);
#pragma unroll
      for (int c = 0; c < 8; ++c){
        unsigned xc = (c&1)?X1:X0;
        unsigned yc = (c&2)?Y1:Y0;
        unsigned zc = (c&4)?Z1:Z0;
        unsigned idx = dense ? (xc+yc+zc) : ((xc^yc^zc)&16383u);
        float2 tv = tl[idx];
        float wc = ((c&1)?wx:wx0) * ((c&2)?wy:wy0) * ((c&4)?wz:wz0);
        f0 += wc*tv.x;
        f1 += wc*tv.y;
      }
      bfrag[2*d]   = (__bf16)f0;
      bfrag[2*d+1] = (__bf16)f1;
    }

    // ---- L1: 32->64, relu ----
    {
      f4 acc[4];
#pragma unroll
      for (int t = 0; t < 4; ++t){
        f4 c = {0.f,0.f,0.f,0.f};
        acc[t] = MFMA16(*(const bf8*)(smem + OFF_W1 + (t*64+lane)*8), bfrag, c);
      }
#pragma unroll
      for (int t = 0; t < 4; ++t){
        us4 pk;
#pragma unroll
        for (int r = 0; r < 4; ++r){
          float v = fmaxf(acc[t][r] + sbias[BO_B1 + t*16 + q*4 + r], 0.f);
          pk[r] = f2bfu(v);
        }
        *(us4*)(act + m*ACT_STRIDE + t*16 + q*4) = pk;
      }
    }
    wfence();   // L1 act write -> L2 read (wave-local)

    // ---- L2: 64->64 relu ----
    layer64(smem+OFF_W2, sbias+BO_B2, act, lane, true);
    wfence();

    // ---- L3: 64->16, no relu; sigma = exp(d[:,0]) ----
    {
      bf8 b0 = *(const bf8*)(act + m*ACT_STRIDE + q*8);
      bf8 b1 = *(const bf8*)(act + m*ACT_STRIDE + 32 + q*8);
      f4 c = {0.f,0.f,0.f,0.f};
      c = MFMA16(*(const bf8*)(smem + OFF_W3 + lane*8), b0, c);
      c = MFMA16(*(const bf8*)(smem + OFF_W3 + (64+lane)*8), b1, c);
      us4 pk;
      float d0 = 0.f;
#pragma unroll
      for (int r = 0; r < 4; ++r){
        float v = c[r] + sbias[BO_B3 + q*4 + r];
        if (r == 0) d0 = v;
        pk[r] = f2bfu(v);
      }
      if (q == 0 && gp < nB) out[gp] = expf(d0);   // row 0 = d[:,0]
      *(us4*)(act + m*ACT_STRIDE + q*4) = pk;      // d features 0..15
    }
    wfence();

    // ---- C1: 16->64 relu (K zero-padded to 32) ----
    {
      bf8 bc;
      if (q < 2){
        bc = *(const bf8*)(act + m*ACT_STRIDE + q*8);
      } else {
#pragma unroll
        for (int j = 0; j < 8; ++j) bc[j] = (__bf16)0.f;
      }
      f4 acc[4];
#pragma unroll
      for (int t = 0; t < 4; ++t){
        f4 c = {0.f,0.f,0.f,0.f};
        acc[t] = MFMA16(*(const bf8*)(smem + OFF_CW1 + (t*64+lane)*8), bc, c);
      }
#pragma unroll
      for (int t = 0; t < 4; ++t){
        us4 pk;
#pragma unroll
        for (int r = 0; r < 4; ++r){
          float v = fmaxf(acc[t][r] + sbias[BO_CB1 + t*16 + q*4 + r], 0.f);
          pk[r] = f2bfu(v);
        }
        *(us4*)(act + m*ACT_STRIDE + t*16 + q*4) = pk;
      }
    }
    wfence();

    // ---- C2, C3: 64->64 relu ----
    layer64(smem+OFF_CW2, sbias+BO_CB2, act, lane, true);
    wfence();
    layer64(smem+OFF_CW3, sbias+BO_CB3, act, lane, true);
    wfence();

    // ---- C4: 64->3, sigmoid ----
    {
      bf8 b0 = *(const bf8*)(act + m*ACT_STRIDE + q*8);
      bf8 b1 = *(const bf8*)(act + m*ACT_STRIDE + 32 + q*8);
      f4 c = {0.f,0.f,0.f,0.f};
      c = MFMA16(*(const bf8*)(smem + OFF_CW4 + lane*8), b0, c);
      c = MFMA16(*(const bf8*)(smem + OFF_CW4 + (64+lane)*8), b1, c);
      if (q == 0 && gp < nB){
#pragma unroll
        for (int r = 0; r < 3; ++r){
          float v = c[r] + sbias[BO_CB4 + r];
          out[nB + gp*3 + r] = 1.f/(1.f + expf(-v));
        }
      }
    }
    wfence();   // C4 act read -> next iter L1 write (wave-local)
  }
}

extern "C" void kernel_launch(void* const* d_in, const int* in_sizes, int n_in,
                              void* d_out, int out_size, void* d_ws, size_t ws_size,
                              hipStream_t stream) {
  (void)n_in; (void)out_size; (void)d_ws; (void)ws_size;
  const int nB = in_sizes[0] / 3;
  const int pts_per_block = BLOCK;     // 16 waves x 64 points
  const int blocks = (nB + pts_per_block - 1) / pts_per_block;
  nerf_fused<<<dim3(blocks), dim3(BLOCK), 0, stream>>>(
      (const float*)d_in[0],  (const float*)d_in[1],
      (const float*)d_in[2],  (const float*)d_in[3],
      (const float*)d_in[4],  (const float*)d_in[5],
      (const float*)d_in[6],  (const float*)d_in[7],
      (const float*)d_in[8],  (const float*)d_in[9],
      (const float*)d_in[10], (const float*)d_in[11],
      (const float*)d_in[12], (const float*)d_in[13],
      (const float*)d_in[14], (const float*)d_in[15],
      (float*)d_out, nB);
}

// Round 7
// 516.332 us; speedup vs baseline: 1.2385x; 1.2385x over previous
//
#include <hip/hip_runtime.h>

typedef __bf16 bf8 __attribute__((ext_vector_type(8)));
typedef float f4 __attribute__((ext_vector_type(4)));
typedef unsigned short us4 __attribute__((ext_vector_type(4)));

#define MFMA16(a,b,c) __builtin_amdgcn_mfma_f32_16x16x32_bf16((a),(b),(c),0,0,0)

#define BLOCK 512
#define NWAVE 8   // waves per block; LDS ~54.0 KB -> 3 blocks/CU -> 24 waves/CU

__device__ __forceinline__ unsigned short f2bfu(float f){
  __bf16 h = (__bf16)f;
  union { __bf16 b; unsigned short u; } v; v.b = h; return v.u;
}
__device__ __forceinline__ float ubfu(unsigned short u){
  union { unsigned int i; float f; } v; v.i = ((unsigned int)u) << 16; return v.f;
}

// Wave-local LDS fence: stalls only THIS wave until its DS ops completed.
// Act buffers are wave-private, so this replaces __syncthreads() between
// layers (validated correct rounds 4-6, absmax 0.0).
__device__ __forceinline__ void wfence(){
  asm volatile("s_waitcnt lgkmcnt(0)" ::: "memory");
}

// LDS layout (ushort element offsets)
#define OFF_W1   0       // 32->64 : 1 kstep * 4 mtiles * 512 = 2048
#define OFF_W2   2048    // 64->64 : 2*4*512 = 4096
#define OFF_W3   6144    // 64->16 : 2*1*512 = 1024
#define OFF_CW1  7168    // 16->64 COMPACT: only k<16 half (lanes q<2): 4*32*8 = 1024
#define OFF_CW2  8192    // 64->64 : 4096
#define OFF_CW3  12288   // 64->64 : 4096
#define OFF_CW4  16384   // 64->3  : 2*1*512 = 1024 (zero-padded M)
#define OFF_ACT  17408
#define ACT_STRIDE 72    // 64 features + 8 pad (keeps b128 align, even banks)
#define SMEM_US  (17408 + NWAVE*16*ACT_STRIDE)   // 26624 shorts = 53248 B

// bias offsets (bf16 shorts)
#define BO_B1  0
#define BO_B2  64
#define BO_B3  128
#define BO_CB1 144
#define BO_CB2 208
#define BO_CB3 272
#define BO_CB4 336

// Stage weights from global (fin x fout row-major FP32) into LDS as bf16 in
// A-fragment order: element ((s*MT+t)*64+lane)*8+j holds w[k=s*32+(lane>>4)*8+j][o=t*16+(lane&15)].
template<int FIN,int FOUT,int KS,int MT>
__device__ __forceinline__ void stage_w(const float* w, unsigned short* dst){
  const int total = KS*MT*512;
  for (int e = threadIdx.x; e < total; e += BLOCK){
    int chunk = e >> 9;
    int s = chunk / MT, t = chunk % MT;
    int le = e & 511;
    int lane = le >> 3, j = le & 7;
    int q = lane >> 4, m = lane & 15;
    int i = s*32 + q*8 + j;
    int o = t*16 + m;
    dst[e] = (i < FIN && o < FOUT) ? f2bfu(w[i*FOUT + o]) : (unsigned short)0;
  }
}

// Compact CW1 (16->64): only lanes 0..31 (k<16) hold data; element
// (t*32+lane)*8+j = w[k=(lane>>4)*8+j][o=t*16+(lane&15)].
__device__ __forceinline__ void stage_cw1(const float* w, unsigned short* dst){
  for (int e = threadIdx.x; e < 1024; e += BLOCK){
    int t = e >> 8;
    int le = e & 255;
    int lane = le >> 3, j = e & 7;     // lane 0..31
    int q = lane >> 4, m = lane & 15;  // q 0..1
    dst[e] = f2bfu(w[(q*8+j)*64 + t*16 + m]);
  }
}

// One 64->64 layer for one wave's 16-point tile, LDS act round-trip.
// bias: bf16 in LDS, C-layout-addressable (broadcast reads, no conflicts).
__device__ __forceinline__ void layer64(const unsigned short* wlds, const unsigned short* bias,
                                        unsigned short* act, int lane, bool relu){
  const int q = lane >> 4, m = lane & 15;
  bf8 b0 = *(const bf8*)(act + m*ACT_STRIDE + q*8);        // k = 0..31
  bf8 b1 = *(const bf8*)(act + m*ACT_STRIDE + 32 + q*8);   // k = 32..63
  f4 acc[4];
#pragma unroll
  for (int t = 0; t < 4; ++t){
    f4 c = {0.f,0.f,0.f,0.f};
    c = MFMA16(*(const bf8*)(wlds + ((0*4+t)*64+lane)*8), b0, c);
    c = MFMA16(*(const bf8*)(wlds + ((1*4+t)*64+lane)*8), b1, c);
    acc[t] = c;
  }
#pragma unroll
  for (int t = 0; t < 4; ++t){
    us4 bb = *(const us4*)(bias + t*16 + q*4);
    us4 pk;
#pragma unroll
    for (int r = 0; r < 4; ++r){
      float v = acc[t][r] + ubfu(bb[r]);
      if (relu) v = fmaxf(v, 0.f);
      pk[r] = f2bfu(v);
    }
    *(us4*)(act + m*ACT_STRIDE + t*16 + q*4) = pk;
  }
}

__global__ __launch_bounds__(BLOCK, 6) void nerf_fused(
    const float* __restrict__ xin, const float* __restrict__ tab,
    const float* __restrict__ w1,  const float* __restrict__ b1,
    const float* __restrict__ w2,  const float* __restrict__ b2,
    const float* __restrict__ w3,  const float* __restrict__ b3,
    const float* __restrict__ cw1, const float* __restrict__ cb1,
    const float* __restrict__ cw2, const float* __restrict__ cb2,
    const float* __restrict__ cw3, const float* __restrict__ cb3,
    const float* __restrict__ cw4, const float* __restrict__ cb4,
    float* __restrict__ out, int nB)
{
  __shared__ __align__(16) unsigned short smem[SMEM_US];
  __shared__ __align__(16) unsigned short sbias[344];   // bf16 biases
  __shared__ int sres[16];

  stage_w<32,64,1,4>(w1,  smem+OFF_W1);
  stage_w<64,64,2,4>(w2,  smem+OFF_W2);
  stage_w<64,16,2,1>(w3,  smem+OFF_W3);
  stage_cw1(cw1, smem+OFF_CW1);
  stage_w<64,64,2,4>(cw2, smem+OFF_CW2);
  stage_w<64,64,2,4>(cw3, smem+OFF_CW3);
  stage_w<64, 3,2,1>(cw4, smem+OFF_CW4);
  {
    int t = threadIdx.x;
    if (t < 64){
      sbias[BO_B1 +t] = f2bfu(b1[t]);
      sbias[BO_B2 +t] = f2bfu(b2[t]);
      sbias[BO_CB1+t] = f2bfu(cb1[t]);
      sbias[BO_CB2+t] = f2bfu(cb2[t]);
      sbias[BO_CB3+t] = f2bfu(cb3[t]);
    }
    if (t < 16) sbias[BO_B3+t] = f2bfu(b3[t]);
    if (t < 3)  sbias[BO_CB4+t] = f2bfu(cb4[t]);
    if (t < 16){
      const int RES_[16] = {16,20,25,32,40,50,64,80,101,128,161,203,256,322,406,512};
      sres[t] = RES_[t];
    }
  }
  __syncthreads();   // weights/bias staging -> everything (only block barrier)

  const int lane = threadIdx.x & 63, wv = threadIdx.x >> 6;
  const int q = lane >> 4, m = lane & 15;
  unsigned short* act = smem + OFF_ACT + wv*16*ACT_STRIDE;

  int res_[4];
#pragma unroll
  for (int d = 0; d < 4; ++d) res_[d] = sres[4*q + d];

  for (int it = 0; it < 4; ++it){
    const int gp  = blockIdx.x*BLOCK + wv*64 + it*16 + m;  // block covers 512 points
    const int gpl = min(gp, nB-1);
    const float px = xin[gpl*3+0];
    const float py = xin[gpl*3+1];
    const float pz = xin[gpl*3+2];

    // ---- hash encode: this lane's 8 features ARE its layer-1 B-fragment ----
    bf8 bfrag;
#pragma unroll
    for (int d = 0; d < 4; ++d){
      const int lvl = 4*q + d;
      const int res = res_[d];
      const float sc = 0.5f*(float)(res-1);
      const float xs=(px+1.f)*sc, ys=(py+1.f)*sc, zs=(pz+1.f)*sc;
      const float fx=floorf(xs), fy=floorf(ys), fz=floorf(zs);
      const float wx=xs-fx, wy=ys-fy, wz=zs-fz;
      int ix0=min(max((int)fx,0),res-1);
      int iy0=min(max((int)fy,0),res-1);
      int iz0=min(max((int)fz,0),res-1);
      int ix1=min(ix0+1,res-1), iy1=min(iy0+1,res-1), iz1=min(iz0+1,res-1);
      const bool dense = (lvl < 3);   // 16^3,20^3,25^3 <= 16384
      unsigned X0,X1,Y0,Y1,Z0,Z1;
      if (dense){
        X0=(unsigned)ix0;            X1=(unsigned)ix1;
        Y0=(unsigned)(res*iy0);      Y1=(unsigned)(res*iy1);
        Z0=(unsigned)(res*res*iz0);  Z1=(unsigned)(res*res*iz1);
      } else {
        X0=(unsigned)ix0;                 X1=(unsigned)ix1;
        Y0=(unsigned)iy0*2654435761u;     Y1=(unsigned)iy1*2654435761u;
        Z0=(unsigned)iz0*805459861u;      Z1=(unsigned)iz1*805459861u;
      }
      const float wx0=1.f-wx, wy0=1.f-wy, wz0=1.f-wz;
      float f0=0.f, f1=0.f;
      const float2* tl = (const float2*)tab + (lvl<<14);
#pragma unroll
      for (int c = 0; c < 8; ++c){
        unsigned xc = (c&1)?X1:X0;
        unsigned yc = (c&2)?Y1:Y0;
        unsigned zc = (c&4)?Z1:Z0;
        unsigned idx = dense ? (xc+yc+zc) : ((xc^yc^zc)&16383u);
        float2 tv = tl[idx];
        float wc = ((c&1)?wx:wx0) * ((c&2)?wy:wy0) * ((c&4)?wz:wz0);
        f0 += wc*tv.x;
        f1 += wc*tv.y;
      }
      bfrag[2*d]   = (__bf16)f0;
      bfrag[2*d+1] = (__bf16)f1;
    }

    // ---- L1: 32->64, relu ----
    {
      f4 acc[4];
#pragma unroll
      for (int t = 0; t < 4; ++t){
        f4 c = {0.f,0.f,0.f,0.f};
        acc[t] = MFMA16(*(const bf8*)(smem + OFF_W1 + (t*64+lane)*8), bfrag, c);
      }
#pragma unroll
      for (int t = 0; t < 4; ++t){
        us4 bb = *(const us4*)(sbias + BO_B1 + t*16 + q*4);
        us4 pk;
#pragma unroll
        for (int r = 0; r < 4; ++r){
          float v = fmaxf(acc[t][r] + ubfu(bb[r]), 0.f);
          pk[r] = f2bfu(v);
        }
        *(us4*)(act + m*ACT_STRIDE + t*16 + q*4) = pk;
      }
    }
    wfence();   // L1 act write -> L2 read (wave-local)

    // ---- L2: 64->64 relu ----
    layer64(smem+OFF_W2, sbias+BO_B2, act, lane, true);
    wfence();

    // ---- L3: 64->16, no relu; sigma = exp(d[:,0]) ----
    {
      bf8 b0 = *(const bf8*)(act + m*ACT_STRIDE + q*8);
      bf8 b1 = *(const bf8*)(act + m*ACT_STRIDE + 32 + q*8);
      f4 c = {0.f,0.f,0.f,0.f};
      c = MFMA16(*(const bf8*)(smem + OFF_W3 + lane*8), b0, c);
      c = MFMA16(*(const bf8*)(smem + OFF_W3 + (64+lane)*8), b1, c);
      us4 bb = *(const us4*)(sbias + BO_B3 + q*4);
      us4 pk;
      float d0 = 0.f;
#pragma unroll
      for (int r = 0; r < 4; ++r){
        float v = c[r] + ubfu(bb[r]);
        if (r == 0) d0 = v;
        pk[r] = f2bfu(v);
      }
      if (q == 0 && gp < nB) out[gp] = expf(d0);   // row 0 = d[:,0]
      *(us4*)(act + m*ACT_STRIDE + q*4) = pk;      // d features 0..15
    }
    wfence();

    // ---- C1: 16->64 relu (K zero-padded to 32; compact weights, q>=2 lanes
    //      contribute zero A and zero B fragments) ----
    {
      bf8 bc, aw[4];
      if (q < 2){
        bc = *(const bf8*)(act + m*ACT_STRIDE + q*8);
#pragma unroll
        for (int t = 0; t < 4; ++t)
          aw[t] = *(const bf8*)(smem + OFF_CW1 + (t*32+lane)*8);
      } else {
#pragma unroll
        for (int j = 0; j < 8; ++j) bc[j] = (__bf16)0.f;
#pragma unroll
        for (int t = 0; t < 4; ++t) aw[t] = bc;
      }
      f4 acc[4];
#pragma unroll
      for (int t = 0; t < 4; ++t){
        f4 c = {0.f,0.f,0.f,0.f};
        acc[t] = MFMA16(aw[t], bc, c);
      }
#pragma unroll
      for (int t = 0; t < 4; ++t){
        us4 bb = *(const us4*)(sbias + BO_CB1 + t*16 + q*4);
        us4 pk;
#pragma unroll
        for (int r = 0; r < 4; ++r){
          float v = fmaxf(acc[t][r] + ubfu(bb[r]), 0.f);
          pk[r] = f2bfu(v);
        }
        *(us4*)(act + m*ACT_STRIDE + t*16 + q*4) = pk;
      }
    }
    wfence();

    // ---- C2, C3: 64->64 relu ----
    layer64(smem+OFF_CW2, sbias+BO_CB2, act, lane, true);
    wfence();
    layer64(smem+OFF_CW3, sbias+BO_CB3, act, lane, true);
    wfence();

    // ---- C4: 64->3, sigmoid ----
    {
      bf8 b0 = *(const bf8*)(act + m*ACT_STRIDE + q*8);
      bf8 b1 = *(const bf8*)(act + m*ACT_STRIDE + 32 + q*8);
      f4 c = {0.f,0.f,0.f,0.f};
      c = MFMA16(*(const bf8*)(smem + OFF_CW4 + lane*8), b0, c);
      c = MFMA16(*(const bf8*)(smem + OFF_CW4 + (64+lane)*8), b1, c);
      if (q == 0 && gp < nB){
#pragma unroll
        for (int r = 0; r < 3; ++r){
          float v = c[r] + ubfu(sbias[BO_CB4 + r]);
          out[nB + gp*3 + r] = 1.f/(1.f + expf(-v));
        }
      }
    }
    wfence();   // C4 act read -> next iter L1 write (wave-local)
  }
}

extern "C" void kernel_launch(void* const* d_in, const int* in_sizes, int n_in,
                              void* d_out, int out_size, void* d_ws, size_t ws_size,
                              hipStream_t stream) {
  (void)n_in; (void)out_size; (void)d_ws; (void)ws_size;
  const int nB = in_sizes[0] / 3;
  const int pts_per_block = BLOCK;     // 8 waves x 64 points
  const int blocks = (nB + pts_per_block - 1) / pts_per_block;
  nerf_fused<<<dim3(blocks), dim3(BLOCK), 0, stream>>>(
      (const float*)d_in[0],  (const float*)d_in[1],
      (const float*)d_in[2],  (const float*)d_in[3],
      (const float*)d_in[4],  (const float*)d_in[5],
      (const float*)d_in[6],  (const float*)d_in[7],
      (const float*)d_in[8],  (const float*)d_in[9],
      (const float*)d_in[10], (const float*)d_in[11],
      (const float*)d_in[12], (const float*)d_in[13],
      (const float*)d_in[14], (const float*)d_in[15],
      (float*)d_out, nB);
}

// Round 8
// 460.024 us; speedup vs baseline: 1.3900x; 1.1224x over previous
//
#include <hip/hip_runtime.h>

typedef __bf16 bf8 __attribute__((ext_vector_type(8)));
typedef float f4 __attribute__((ext_vector_type(4)));
typedef unsigned short us4 __attribute__((ext_vector_type(4)));

#define MFMA16(a,b,c) __builtin_amdgcn_mfma_f32_16x16x32_bf16((a),(b),(c),0,0,0)

#define BLOCK 512
#define NWAVE 8   // waves per block; LDS ~53 KB -> 3 blocks/CU (VGPR must stay <=64)

__device__ __forceinline__ unsigned short f2bfu(float f){
  __bf16 h = (__bf16)f;
  union { __bf16 b; unsigned short u; } v; v.b = h; return v.u;
}
__device__ __forceinline__ float ubfu(unsigned short u){
  union { unsigned int i; float f; } v; v.i = ((unsigned int)u) << 16; return v.f;
}

// Wave-local LDS fence: stalls only THIS wave until its DS ops completed.
// Act buffers are wave-private, so this replaces __syncthreads() between
// layers (validated correct rounds 4-7, absmax 0.0).
__device__ __forceinline__ void wfence(){
  asm volatile("s_waitcnt lgkmcnt(0)" ::: "memory");
}

// LDS layout (ushort element offsets)
#define OFF_W1   0       // 32->64 : 1 kstep * 4 mtiles * 512 = 2048
#define OFF_W2   2048    // 64->64 : 2*4*512 = 4096
#define OFF_W3   6144    // 64->16 : 2*1*512 = 1024
#define OFF_CW1  7168    // 16->64 COMPACT: only k<16 half (lanes q<2): 4*32*8 = 1024
#define OFF_CW2  8192    // 64->64 : 4096
#define OFF_CW3  12288   // 64->64 : 4096
#define OFF_CW4  16384   // 64->3  : 2*1*512 = 1024 (zero-padded M)
#define OFF_ACT  17408
#define ACT_STRIDE 72    // 64 features + 8 pad (keeps b128 align, even banks)
#define SMEM_US  (17408 + NWAVE*16*ACT_STRIDE)   // 26624 shorts = 53248 B

// bias offsets (bf16 shorts)
#define BO_B1  0
#define BO_B2  64
#define BO_B3  128
#define BO_CB1 144
#define BO_CB2 208
#define BO_CB3 272
#define BO_CB4 336

// Stage weights from global (fin x fout row-major FP32) into LDS as bf16 in
// A-fragment order: element ((s*MT+t)*64+lane)*8+j holds w[k=s*32+(lane>>4)*8+j][o=t*16+(lane&15)].
template<int FIN,int FOUT,int KS,int MT>
__device__ __forceinline__ void stage_w(const float* w, unsigned short* dst){
  const int total = KS*MT*512;
  for (int e = threadIdx.x; e < total; e += BLOCK){
    int chunk = e >> 9;
    int s = chunk / MT, t = chunk % MT;
    int le = e & 511;
    int lane = le >> 3, j = le & 7;
    int q = lane >> 4, m = lane & 15;
    int i = s*32 + q*8 + j;
    int o = t*16 + m;
    dst[e] = (i < FIN && o < FOUT) ? f2bfu(w[i*FOUT + o]) : (unsigned short)0;
  }
}

// Compact CW1 (16->64): only lanes 0..31 (k<16) hold data; element
// (t*32+lane)*8+j = w[k=(lane>>4)*8+j][o=t*16+(lane&15)].
__device__ __forceinline__ void stage_cw1(const float* w, unsigned short* dst){
  for (int e = threadIdx.x; e < 1024; e += BLOCK){
    int t = e >> 8;
    int le = e & 255;
    int lane = le >> 3, j = e & 7;     // lane 0..31
    int q = lane >> 4, m = lane & 15;  // q 0..1
    dst[e] = f2bfu(w[(q*8+j)*64 + t*16 + m]);
  }
}

// One 64->64 layer for one wave's 16-point tile, LDS act round-trip.
__device__ __forceinline__ void layer64(const unsigned short* wlds, const unsigned short* bias,
                                        unsigned short* act, int lane, bool relu){
  const int q = lane >> 4, m = lane & 15;
  bf8 b0 = *(const bf8*)(act + m*ACT_STRIDE + q*8);        // k = 0..31
  bf8 b1 = *(const bf8*)(act + m*ACT_STRIDE + 32 + q*8);   // k = 32..63
  f4 acc[4];
#pragma unroll
  for (int t = 0; t < 4; ++t){
    f4 c = {0.f,0.f,0.f,0.f};
    c = MFMA16(*(const bf8*)(wlds + ((0*4+t)*64+lane)*8), b0, c);
    c = MFMA16(*(const bf8*)(wlds + ((1*4+t)*64+lane)*8), b1, c);
    acc[t] = c;
  }
#pragma unroll
  for (int t = 0; t < 4; ++t){
    us4 bb = *(const us4*)(bias + t*16 + q*4);
    us4 pk;
#pragma unroll
    for (int r = 0; r < 4; ++r){
      float v = acc[t][r] + ubfu(bb[r]);
      if (relu) v = fmaxf(v, 0.f);
      pk[r] = f2bfu(v);
    }
    *(us4*)(act + m*ACT_STRIDE + t*16 + q*4) = pk;
  }
}

// NOTE: no min-waves arg — rounds 6/7 proved any occupancy hint collapses the
// arch-VGPR budget below the ~56-reg working set and spills ~400+ MB to scratch.
__global__ __launch_bounds__(BLOCK) void nerf_fused(
    const float* __restrict__ xin, const float* __restrict__ tab,
    const float* __restrict__ w1,  const float* __restrict__ b1,
    const float* __restrict__ w2,  const float* __restrict__ b2,
    const float* __restrict__ w3,  const float* __restrict__ b3,
    const float* __restrict__ cw1, const float* __restrict__ cb1,
    const float* __restrict__ cw2, const float* __restrict__ cb2,
    const float* __restrict__ cw3, const float* __restrict__ cb3,
    const float* __restrict__ cw4, const float* __restrict__ cb4,
    float* __restrict__ out, int nB)
{
  __shared__ __align__(16) unsigned short smem[SMEM_US];
  __shared__ __align__(16) unsigned short sbias[344];   // bf16 biases
  __shared__ int sres[16];

  stage_w<32,64,1,4>(w1,  smem+OFF_W1);
  stage_w<64,64,2,4>(w2,  smem+OFF_W2);
  stage_w<64,16,2,1>(w3,  smem+OFF_W3);
  stage_cw1(cw1, smem+OFF_CW1);
  stage_w<64,64,2,4>(cw2, smem+OFF_CW2);
  stage_w<64,64,2,4>(cw3, smem+OFF_CW3);
  stage_w<64, 3,2,1>(cw4, smem+OFF_CW4);
  {
    int t = threadIdx.x;
    if (t < 64){
      sbias[BO_B1 +t] = f2bfu(b1[t]);
      sbias[BO_B2 +t] = f2bfu(b2[t]);
      sbias[BO_CB1+t] = f2bfu(cb1[t]);
      sbias[BO_CB2+t] = f2bfu(cb2[t]);
      sbias[BO_CB3+t] = f2bfu(cb3[t]);
    }
    if (t < 16) sbias[BO_B3+t] = f2bfu(b3[t]);
    if (t < 3)  sbias[BO_CB4+t] = f2bfu(cb4[t]);
    if (t < 16){
      const int RES_[16] = {16,20,25,32,40,50,64,80,101,128,161,203,256,322,406,512};
      sres[t] = RES_[t];
    }
  }
  __syncthreads();   // weights/bias staging -> everything (only block barrier)

  const int lane = threadIdx.x & 63, wv = threadIdx.x >> 6;
  const int q = lane >> 4, m = lane & 15;
  unsigned short* act = smem + OFF_ACT + wv*16*ACT_STRIDE;

  int res_[4];
#pragma unroll
  for (int d = 0; d < 4; ++d) res_[d] = sres[4*q + d];

  for (int it = 0; it < 4; ++it){
    const int gp  = blockIdx.x*BLOCK + wv*64 + it*16 + m;  // block covers 512 points
    const int gpl = min(gp, nB-1);
    const float px = xin[gpl*3+0];
    const float py = xin[gpl*3+1];
    const float pz = xin[gpl*3+2];

    // ---- hash encode: this lane's 8 features ARE its layer-1 B-fragment ----
    bf8 bfrag;
#pragma unroll
    for (int d = 0; d < 4; ++d){
      const int lvl = 4*q + d;
      const int res = res_[d];
      const float sc = 0.5f*(float)(res-1);
      const float xs=(px+1.f)*sc, ys=(py+1.f)*sc, zs=(pz+1.f)*sc;
      const float fx=floorf(xs), fy=floorf(ys), fz=floorf(zs);
      const float wx=xs-fx, wy=ys-fy, wz=zs-fz;
      int ix0=min(max((int)fx,0),res-1);
      int iy0=min(max((int)fy,0),res-1);
      int iz0=min(max((int)fz,0),res-1);
      int ix1=min(ix0+1,res-1), iy1=min(iy0+1,res-1), iz1=min(iz0+1,res-1);
      const bool dense = (lvl < 3);   // 16^3,20^3,25^3 <= 16384
      unsigned X0,X1,Y0,Y1,Z0,Z1;
      if (dense){
        X0=(unsigned)ix0;            X1=(unsigned)ix1;
        Y0=(unsigned)(res*iy0);      Y1=(unsigned)(res*iy1);
        Z0=(unsigned)(res*res*iz0);  Z1=(unsigned)(res*res*iz1);
      } else {
        X0=(unsigned)ix0;                 X1=(unsigned)ix1;
        Y0=(unsigned)iy0*2654435761u;     Y1=(unsigned)iy1*2654435761u;
        Z0=(unsigned)iz0*805459861u;      Z1=(unsigned)iz1*805459861u;
      }
      const float wx0=1.f-wx, wy0=1.f-wy, wz0=1.f-wz;
      float f0=0.f, f1=0.f;
      const float2* tl = (const float2*)tab + (lvl<<14);
#pragma unroll
      for (int c = 0; c < 8; ++c){
        unsigned xc = (c&1)?X1:X0;
        unsigned yc = (c&2)?Y1:Y0;
        unsigned zc = (c&4)?Z1:Z0;
        unsigned idx = dense ? (xc+yc+zc) : ((xc^yc^zc)&16383u);
        float2 tv = tl[idx];
        float wc = ((c&1)?wx:wx0) * ((c&2)?wy:wy0) * ((c&4)?wz:wz0);
        f0 += wc*tv.x;
        f1 += wc*tv.y;
      }
      bfrag[2*d]   = (__bf16)f0;
      bfrag[2*d+1] = (__bf16)f1;
    }

    // ---- L1: 32->64, relu ----
    {
      f4 acc[4];
#pragma unroll
      for (int t = 0; t < 4; ++t){
        f4 c = {0.f,0.f,0.f,0.f};
        acc[t] = MFMA16(*(const bf8*)(smem + OFF_W1 + (t*64+lane)*8), bfrag, c);
      }
#pragma unroll
      for (int t = 0; t < 4; ++t){
        us4 bb = *(const us4*)(sbias + BO_B1 + t*16 + q*4);
        us4 pk;
#pragma unroll
        for (int r = 0; r < 4; ++r){
          float v = fmaxf(acc[t][r] + ubfu(bb[r]), 0.f);
          pk[r] = f2bfu(v);
        }
        *(us4*)(act + m*ACT_STRIDE + t*16 + q*4) = pk;
      }
    }
    wfence();   // L1 act write -> L2 read (wave-local)

    // ---- L2: 64->64 relu ----
    layer64(smem+OFF_W2, sbias+BO_B2, act, lane, true);
    wfence();

    // ---- L3: 64->16, no relu; sigma = exp(d[:,0]) ----
    {
      bf8 b0 = *(const bf8*)(act + m*ACT_STRIDE + q*8);
      bf8 b1 = *(const bf8*)(act + m*ACT_STRIDE + 32 + q*8);
      f4 c = {0.f,0.f,0.f,0.f};
      c = MFMA16(*(const bf8*)(smem + OFF_W3 + lane*8), b0, c);
      c = MFMA16(*(const bf8*)(smem + OFF_W3 + (64+lane)*8), b1, c);
      us4 bb = *(const us4*)(sbias + BO_B3 + q*4);
      us4 pk;
      float d0 = 0.f;
#pragma unroll
      for (int r = 0; r < 4; ++r){
        float v = c[r] + ubfu(bb[r]);
        if (r == 0) d0 = v;
        pk[r] = f2bfu(v);
      }
      if (q == 0 && gp < nB) out[gp] = expf(d0);   // row 0 = d[:,0]
      *(us4*)(act + m*ACT_STRIDE + q*4) = pk;      // d features 0..15
    }
    wfence();

    // ---- C1: 16->64 relu (compact weights; q>=2 lanes feed zero frags) ----
    {
      bf8 bc, aw[4];
      if (q < 2){
        bc = *(const bf8*)(act + m*ACT_STRIDE + q*8);
#pragma unroll
        for (int t = 0; t < 4; ++t)
          aw[t] = *(const bf8*)(smem + OFF_CW1 + (t*32+lane)*8);
      } else {
#pragma unroll
        for (int j = 0; j < 8; ++j) bc[j] = (__bf16)0.f;
#pragma unroll
        for (int t = 0; t < 4; ++t) aw[t] = bc;
      }
      f4 acc[4];
#pragma unroll
      for (int t = 0; t < 4; ++t){
        f4 c = {0.f,0.f,0.f,0.f};
        acc[t] = MFMA16(aw[t], bc, c);
      }
#pragma unroll
      for (int t = 0; t < 4; ++t){
        us4 bb = *(const us4*)(sbias + BO_CB1 + t*16 + q*4);
        us4 pk;
#pragma unroll
        for (int r = 0; r < 4; ++r){
          float v = fmaxf(acc[t][r] + ubfu(bb[r]), 0.f);
          pk[r] = f2bfu(v);
        }
        *(us4*)(act + m*ACT_STRIDE + t*16 + q*4) = pk;
      }
    }
    wfence();

    // ---- C2, C3: 64->64 relu ----
    layer64(smem+OFF_CW2, sbias+BO_CB2, act, lane, true);
    wfence();
    layer64(smem+OFF_CW3, sbias+BO_CB3, act, lane, true);
    wfence();

    // ---- C4: 64->3, sigmoid ----
    {
      bf8 b0 = *(const bf8*)(act + m*ACT_STRIDE + q*8);
      bf8 b1 = *(const bf8*)(act + m*ACT_STRIDE + 32 + q*8);
      f4 c = {0.f,0.f,0.f,0.f};
      c = MFMA16(*(const bf8*)(smem + OFF_CW4 + lane*8), b0, c);
      c = MFMA16(*(const bf8*)(smem + OFF_CW4 + (64+lane)*8), b1, c);
      if (q == 0 && gp < nB){
#pragma unroll
        for (int r = 0; r < 3; ++r){
          float v = c[r] + ubfu(sbias[BO_CB4 + r]);
          out[nB + gp*3 + r] = 1.f/(1.f + expf(-v));
        }
      }
    }
    wfence();   // C4 act read -> next iter L1 write (wave-local)
  }
}

extern "C" void kernel_launch(void* const* d_in, const int* in_sizes, int n_in,
                              void* d_out, int out_size, void* d_ws, size_t ws_size,
                              hipStream_t stream) {
  (void)n_in; (void)out_size; (void)d_ws; (void)ws_size;
  const int nB = in_sizes[0] / 3;
  const int pts_per_block = BLOCK;     // 8 waves x 64 points
  const int blocks = (nB + pts_per_block - 1) / pts_per_block;
  nerf_fused<<<dim3(blocks), dim3(BLOCK), 0, stream>>>(
      (const float*)d_in[0],  (const float*)d_in[1],
      (const float*)d_in[2],  (const float*)d_in[3],
      (const float*)d_in[4],  (const float*)d_in[5],
      (const float*)d_in[6],  (const float*)d_in[7],
      (const float*)d_in[8],  (const float*)d_in[9],
      (const float*)d_in[10], (const float*)d_in[11],
      (const float*)d_in[12], (const float*)d_in[13],
      (const float*)d_in[14], (const float*)d_in[15],
      (float*)d_out, nB);
}

// Round 9
// 197.094 us; speedup vs baseline: 3.2444x; 2.3340x over previous
//
#include <hip/hip_runtime.h>

typedef __bf16 bf8 __attribute__((ext_vector_type(8)));
typedef float f4 __attribute__((ext_vector_type(4)));
typedef unsigned short us4 __attribute__((ext_vector_type(4)));
typedef unsigned int u32x4 __attribute__((ext_vector_type(4)));

#define MFMA16(a,b,c) __builtin_amdgcn_mfma_f32_16x16x32_bf16((a),(b),(c),0,0,0)

#define BLOCK 512
#define NWAVE 8

__device__ __forceinline__ unsigned short f2bfu(float f){
  __bf16 h = (__bf16)f;
  union { __bf16 b; unsigned short u; } v; v.b = h; return v.u;
}
__device__ __forceinline__ float ubfu(unsigned int u16){
  union { unsigned int i; float f; } v; v.i = u16 << 16; return v.f;
}

// Wave-local LDS fence (validated rounds 4-8, absmax 0.0).
__device__ __forceinline__ void wfence(){
  asm volatile("s_waitcnt lgkmcnt(0)" ::: "memory");
}

// LDS layout for MLP kernels (ushort element offsets)
#define OFF_W1   0
#define OFF_W2   2048
#define OFF_W3   6144
#define OFF_CW1  7168    // compact: k<16 half only
#define OFF_CW2  8192
#define OFF_CW3  12288
#define OFF_CW4  16384
#define OFF_ACT  17408
#define ACT_STRIDE 72
#define SMEM_US  (17408 + NWAVE*16*ACT_STRIDE)   // 53248 B

#define BO_B1  0
#define BO_B2  64
#define BO_B3  128
#define BO_CB1 144
#define BO_CB2 208
#define BO_CB3 272
#define BO_CB4 336

template<int FIN,int FOUT,int KS,int MT>
__device__ __forceinline__ void stage_w(const float* w, unsigned short* dst){
  const int total = KS*MT*512;
  for (int e = threadIdx.x; e < total; e += BLOCK){
    int chunk = e >> 9;
    int s = chunk / MT, t = chunk % MT;
    int le = e & 511;
    int lane = le >> 3, j = le & 7;
    int q = lane >> 4, m = lane & 15;
    int i = s*32 + q*8 + j;
    int o = t*16 + m;
    dst[e] = (i < FIN && o < FOUT) ? f2bfu(w[i*FOUT + o]) : (unsigned short)0;
  }
}

__device__ __forceinline__ void stage_cw1(const float* w, unsigned short* dst){
  for (int e = threadIdx.x; e < 1024; e += BLOCK){
    int t = e >> 8;
    int le = e & 255;
    int lane = le >> 3, j = e & 7;
    int q = lane >> 4, m = lane & 15;
    dst[e] = f2bfu(w[(q*8+j)*64 + t*16 + m]);
  }
}

__device__ __forceinline__ void layer64(const unsigned short* wlds, const unsigned short* bias,
                                        unsigned short* act, int lane, bool relu){
  const int q = lane >> 4, m = lane & 15;
  bf8 b0 = *(const bf8*)(act + m*ACT_STRIDE + q*8);
  bf8 b1 = *(const bf8*)(act + m*ACT_STRIDE + 32 + q*8);
  f4 acc[4];
#pragma unroll
  for (int t = 0; t < 4; ++t){
    f4 c = {0.f,0.f,0.f,0.f};
    c = MFMA16(*(const bf8*)(wlds + ((0*4+t)*64+lane)*8), b0, c);
    c = MFMA16(*(const bf8*)(wlds + ((1*4+t)*64+lane)*8), b1, c);
    acc[t] = c;
  }
#pragma unroll
  for (int t = 0; t < 4; ++t){
    us4 bb = *(const us4*)(bias + t*16 + q*4);
    us4 pk;
#pragma unroll
    for (int r = 0; r < 4; ++r){
      float v = acc[t][r] + ubfu(bb[r]);
      if (relu) v = fmaxf(v, 0.f);
      pk[r] = f2bfu(v);
    }
    *(us4*)(act + m*ACT_STRIDE + t*16 + q*4) = pk;
  }
}

// Shared device code for the bias/weight staging preamble.
#define STAGE_ALL_WEIGHTS()                                                  \
  stage_w<32,64,1,4>(w1,  smem+OFF_W1);                                      \
  stage_w<64,64,2,4>(w2,  smem+OFF_W2);                                      \
  stage_w<64,16,2,1>(w3,  smem+OFF_W3);                                      \
  stage_cw1(cw1, smem+OFF_CW1);                                              \
  stage_w<64,64,2,4>(cw2, smem+OFF_CW2);                                     \
  stage_w<64,64,2,4>(cw3, smem+OFF_CW3);                                     \
  stage_w<64, 3,2,1>(cw4, smem+OFF_CW4);                                     \
  {                                                                          \
    int t = threadIdx.x;                                                     \
    if (t < 64){                                                             \
      sbias[BO_B1 +t] = f2bfu(b1[t]);                                        \
      sbias[BO_B2 +t] = f2bfu(b2[t]);                                        \
      sbias[BO_CB1+t] = f2bfu(cb1[t]);                                       \
      sbias[BO_CB2+t] = f2bfu(cb2[t]);                                       \
      sbias[BO_CB3+t] = f2bfu(cb3[t]);                                       \
    }                                                                        \
    if (t < 16) sbias[BO_B3+t] = f2bfu(b3[t]);                               \
    if (t < 3)  sbias[BO_CB4+t] = f2bfu(cb4[t]);                             \
  }

// The MLP body for one iteration, starting from bfrag. Defined as a macro so
// fused and two-phase kernels share it exactly.
#define MLP_BODY(bfrag, gp)                                                  \
    {                                                                        \
      f4 acc[4];                                                             \
      _Pragma("unroll")                                                      \
      for (int t = 0; t < 4; ++t){                                           \
        f4 c = {0.f,0.f,0.f,0.f};                                            \
        acc[t] = MFMA16(*(const bf8*)(smem + OFF_W1 + (t*64+lane)*8), bfrag, c);\
      }                                                                      \
      _Pragma("unroll")                                                      \
      for (int t = 0; t < 4; ++t){                                           \
        us4 bb = *(const us4*)(sbias + BO_B1 + t*16 + q*4);                  \
        us4 pk;                                                              \
        _Pragma("unroll")                                                    \
        for (int r = 0; r < 4; ++r){                                         \
          float v = fmaxf(acc[t][r] + ubfu(bb[r]), 0.f);                     \
          pk[r] = f2bfu(v);                                                  \
        }                                                                    \
        *(us4*)(act + m*ACT_STRIDE + t*16 + q*4) = pk;                       \
      }                                                                      \
    }                                                                        \
    wfence();                                                                \
    layer64(smem+OFF_W2, sbias+BO_B2, act, lane, true);                      \
    wfence();                                                                \
    {                                                                        \
      bf8 b0 = *(const bf8*)(act + m*ACT_STRIDE + q*8);                      \
      bf8 b1 = *(const bf8*)(act + m*ACT_STRIDE + 32 + q*8);                 \
      f4 c = {0.f,0.f,0.f,0.f};                                              \
      c = MFMA16(*(const bf8*)(smem + OFF_W3 + lane*8), b0, c);              \
      c = MFMA16(*(const bf8*)(smem + OFF_W3 + (64+lane)*8), b1, c);         \
      us4 bb = *(const us4*)(sbias + BO_B3 + q*4);                           \
      us4 pk;                                                                \
      float d0 = 0.f;                                                        \
      _Pragma("unroll")                                                      \
      for (int r = 0; r < 4; ++r){                                           \
        float v = c[r] + ubfu(bb[r]);                                        \
        if (r == 0) d0 = v;                                                  \
        pk[r] = f2bfu(v);                                                    \
      }                                                                      \
      if (q == 0 && gp < nB) out[gp] = expf(d0);                             \
      *(us4*)(act + m*ACT_STRIDE + q*4) = pk;                                \
    }                                                                        \
    wfence();                                                                \
    {                                                                        \
      bf8 bc, aw[4];                                                         \
      if (q < 2){                                                            \
        bc = *(const bf8*)(act + m*ACT_STRIDE + q*8);                        \
        _Pragma("unroll")                                                    \
        for (int t = 0; t < 4; ++t)                                          \
          aw[t] = *(const bf8*)(smem + OFF_CW1 + (t*32+lane)*8);             \
      } else {                                                               \
        _Pragma("unroll")                                                    \
        for (int j = 0; j < 8; ++j) bc[j] = (__bf16)0.f;                     \
        _Pragma("unroll")                                                    \
        for (int t = 0; t < 4; ++t) aw[t] = bc;                              \
      }                                                                      \
      f4 acc[4];                                                             \
      _Pragma("unroll")                                                      \
      for (int t = 0; t < 4; ++t){                                           \
        f4 c = {0.f,0.f,0.f,0.f};                                            \
        acc[t] = MFMA16(aw[t], bc, c);                                       \
      }                                                                      \
      _Pragma("unroll")                                                      \
      for (int t = 0; t < 4; ++t){                                           \
        us4 bb = *(const us4*)(sbias + BO_CB1 + t*16 + q*4);                 \
        us4 pk;                                                              \
        _Pragma("unroll")                                                    \
        for (int r = 0; r < 4; ++r){                                         \
          float v = fmaxf(acc[t][r] + ubfu(bb[r]), 0.f);                     \
          pk[r] = f2bfu(v);                                                  \
        }                                                                    \
        *(us4*)(act + m*ACT_STRIDE + t*16 + q*4) = pk;                       \
      }                                                                      \
    }                                                                        \
    wfence();                                                                \
    layer64(smem+OFF_CW2, sbias+BO_CB2, act, lane, true);                    \
    wfence();                                                                \
    layer64(smem+OFF_CW3, sbias+BO_CB3, act, lane, true);                    \
    wfence();                                                                \
    {                                                                        \
      bf8 b0 = *(const bf8*)(act + m*ACT_STRIDE + q*8);                      \
      bf8 b1 = *(const bf8*)(act + m*ACT_STRIDE + 32 + q*8);                 \
      f4 c = {0.f,0.f,0.f,0.f};                                              \
      c = MFMA16(*(const bf8*)(smem + OFF_CW4 + lane*8), b0, c);             \
      c = MFMA16(*(const bf8*)(smem + OFF_CW4 + (64+lane)*8), b1, c);        \
      if (q == 0 && gp < nB){                                                \
        _Pragma("unroll")                                                    \
        for (int r = 0; r < 3; ++r){                                         \
          float v = c[r] + ubfu(sbias[BO_CB4 + r]);                          \
          out[nB + gp*3 + r] = 1.f/(1.f + expf(-v));                         \
        }                                                                    \
      }                                                                      \
    }                                                                        \
    wfence();

// ---------------------------------------------------------------------------
// Phase A: per-level hash encode with the level's FULL table in LDS (bf16x2
// packed, 64 KB). Kills the 64B-line L2 amplification: gathers are 4B LDS ops.
// grid = (point chunks, 16 levels). feat layout: [level][point] packed uint.
// ---------------------------------------------------------------------------
#define CH 16384
__global__ __launch_bounds__(512) void hash_phase(
    const float* __restrict__ xin, const float* __restrict__ tab,
    unsigned int* __restrict__ feat, int nB)
{
  __shared__ unsigned int stab[16384];
  __shared__ int sres[16];
  const int lvl = blockIdx.y;
  {
    const float2* t2 = (const float2*)tab + (lvl<<14);
    for (int e = threadIdx.x; e < 16384; e += 512){
      float2 v = t2[e];
      stab[e] = ((unsigned)f2bfu(v.y) << 16) | (unsigned)f2bfu(v.x);
    }
    if (threadIdx.x < 16){
      const int R[16] = {16,20,25,32,40,50,64,80,101,128,161,203,256,322,406,512};
      sres[threadIdx.x] = R[threadIdx.x];
    }
  }
  __syncthreads();

  const int res = sres[lvl];
  const float sc = 0.5f*(float)(res-1);
  const bool dense = (lvl < 3);              // 16^3,20^3,25^3 <= 16384
  unsigned int* fout = feat + (size_t)lvl * (size_t)nB;

  int pend = (blockIdx.x + 1) * CH; if (pend > nB) pend = nB;
  for (int p = blockIdx.x*CH + threadIdx.x; p < pend; p += 512){
    const float px = xin[p*3+0], py = xin[p*3+1], pz = xin[p*3+2];
    const float xs=(px+1.f)*sc, ys=(py+1.f)*sc, zs=(pz+1.f)*sc;
    const float fx=floorf(xs), fy=floorf(ys), fz=floorf(zs);
    const float wx=xs-fx, wy=ys-fy, wz=zs-fz;
    int ix0=min(max((int)fx,0),res-1);
    int iy0=min(max((int)fy,0),res-1);
    int iz0=min(max((int)fz,0),res-1);
    int ix1=min(ix0+1,res-1), iy1=min(iy0+1,res-1), iz1=min(iz0+1,res-1);
    unsigned X0,X1,Y0,Y1,Z0,Z1;
    if (dense){
      X0=(unsigned)ix0;            X1=(unsigned)ix1;
      Y0=(unsigned)(res*iy0);      Y1=(unsigned)(res*iy1);
      Z0=(unsigned)(res*res*iz0);  Z1=(unsigned)(res*res*iz1);
    } else {
      X0=(unsigned)ix0;                 X1=(unsigned)ix1;
      Y0=(unsigned)iy0*2654435761u;     Y1=(unsigned)iy1*2654435761u;
      Z0=(unsigned)iz0*805459861u;      Z1=(unsigned)iz1*805459861u;
    }
    const float wx0=1.f-wx, wy0=1.f-wy, wz0=1.f-wz;
    float f0=0.f, f1=0.f;
#pragma unroll
    for (int c = 0; c < 8; ++c){
      unsigned xc = (c&1)?X1:X0;
      unsigned yc = (c&2)?Y1:Y0;
      unsigned zc = (c&4)?Z1:Z0;
      unsigned idx = dense ? (xc+yc+zc) : ((xc^yc^zc)&16383u);
      unsigned tv = stab[idx];
      float wc = ((c&1)?wx:wx0) * ((c&2)?wy:wy0) * ((c&4)?wz:wz0);
      f0 += wc*ubfu(tv << 16);
      f1 += wc*ubfu(tv & 0xffff0000u);
    }
    fout[p] = ((unsigned)f2bfu(f1) << 16) | (unsigned)f2bfu(f0);
  }
}

// ---------------------------------------------------------------------------
// Phase B: MLP over precomputed features. 4 coalesced dword loads per lane
// ARE the L1 B-fragment bits (no repack).
// ---------------------------------------------------------------------------
__global__ __launch_bounds__(BLOCK) void mlp_phase(
    const unsigned int* __restrict__ feat,
    const float* __restrict__ w1,  const float* __restrict__ b1,
    const float* __restrict__ w2,  const float* __restrict__ b2,
    const float* __restrict__ w3,  const float* __restrict__ b3,
    const float* __restrict__ cw1, const float* __restrict__ cb1,
    const float* __restrict__ cw2, const float* __restrict__ cb2,
    const float* __restrict__ cw3, const float* __restrict__ cb3,
    const float* __restrict__ cw4, const float* __restrict__ cb4,
    float* __restrict__ out, int nB)
{
  __shared__ __align__(16) unsigned short smem[SMEM_US];
  __shared__ __align__(16) unsigned short sbias[344];
  STAGE_ALL_WEIGHTS();
  __syncthreads();

  const int lane = threadIdx.x & 63, wv = threadIdx.x >> 6;
  const int q = lane >> 4, m = lane & 15;
  unsigned short* act = smem + OFF_ACT + wv*16*ACT_STRIDE;
  const unsigned int* fq = feat + (size_t)(4*q) * (size_t)nB;

  for (int it = 0; it < 4; ++it){
    const int gp  = blockIdx.x*BLOCK + wv*64 + it*16 + m;
    const int gpl = min(gp, nB-1);
    union { u32x4 u; bf8 b; } fb;
    fb.u[0] = fq[gpl];
    fb.u[1] = fq[(size_t)nB   + gpl];
    fb.u[2] = fq[(size_t)nB*2 + gpl];
    fb.u[3] = fq[(size_t)nB*3 + gpl];
    bf8 bfrag = fb.b;
    MLP_BODY(bfrag, gp)
  }
}

// ---------------------------------------------------------------------------
// Fallback: round-8 fused kernel (used only if workspace < 64 MB).
// ---------------------------------------------------------------------------
__global__ __launch_bounds__(BLOCK) void nerf_fused(
    const float* __restrict__ xin, const float* __restrict__ tab,
    const float* __restrict__ w1,  const float* __restrict__ b1,
    const float* __restrict__ w2,  const float* __restrict__ b2,
    const float* __restrict__ w3,  const float* __restrict__ b3,
    const float* __restrict__ cw1, const float* __restrict__ cb1,
    const float* __restrict__ cw2, const float* __restrict__ cb2,
    const float* __restrict__ cw3, const float* __restrict__ cb3,
    const float* __restrict__ cw4, const float* __restrict__ cb4,
    float* __restrict__ out, int nB)
{
  __shared__ __align__(16) unsigned short smem[SMEM_US];
  __shared__ __align__(16) unsigned short sbias[344];
  __shared__ int sres[16];
  STAGE_ALL_WEIGHTS();
  if (threadIdx.x < 16){
    const int R[16] = {16,20,25,32,40,50,64,80,101,128,161,203,256,322,406,512};
    sres[threadIdx.x] = R[threadIdx.x];
  }
  __syncthreads();

  const int lane = threadIdx.x & 63, wv = threadIdx.x >> 6;
  const int q = lane >> 4, m = lane & 15;
  unsigned short* act = smem + OFF_ACT + wv*16*ACT_STRIDE;

  int res_[4];
#pragma unroll
  for (int d = 0; d < 4; ++d) res_[d] = sres[4*q + d];

  for (int it = 0; it < 4; ++it){
    const int gp  = blockIdx.x*BLOCK + wv*64 + it*16 + m;
    const int gpl = min(gp, nB-1);
    const float px = xin[gpl*3+0];
    const float py = xin[gpl*3+1];
    const float pz = xin[gpl*3+2];

    bf8 bfrag;
#pragma unroll
    for (int d = 0; d < 4; ++d){
      const int lvl = 4*q + d;
      const int res = res_[d];
      const float sc = 0.5f*(float)(res-1);
      const float xs=(px+1.f)*sc, ys=(py+1.f)*sc, zs=(pz+1.f)*sc;
      const float fx=floorf(xs), fy=floorf(ys), fz=floorf(zs);
      const float wx=xs-fx, wy=ys-fy, wz=zs-fz;
      int ix0=min(max((int)fx,0),res-1);
      int iy0=min(max((int)fy,0),res-1);
      int iz0=min(max((int)fz,0),res-1);
      int ix1=min(ix0+1,res-1), iy1=min(iy0+1,res-1), iz1=min(iz0+1,res-1);
      const bool dense = (lvl < 3);
      unsigned X0,X1,Y0,Y1,Z0,Z1;
      if (dense){
        X0=(unsigned)ix0;            X1=(unsigned)ix1;
        Y0=(unsigned)(res*iy0);      Y1=(unsigned)(res*iy1);
        Z0=(unsigned)(res*res*iz0);  Z1=(unsigned)(res*res*iz1);
      } else {
        X0=(unsigned)ix0;                 X1=(unsigned)ix1;
        Y0=(unsigned)iy0*2654435761u;     Y1=(unsigned)iy1*2654435761u;
        Z0=(unsigned)iz0*805459861u;      Z1=(unsigned)iz1*805459861u;
      }
      const float wx0=1.f-wx, wy0=1.f-wy, wz0=1.f-wz;
      float f0=0.f, f1=0.f;
      const float2* tl = (const float2*)tab + (lvl<<14);
#pragma unroll
      for (int c = 0; c < 8; ++c){
        unsigned xc = (c&1)?X1:X0;
        unsigned yc = (c&2)?Y1:Y0;
        unsigned zc = (c&4)?Z1:Z0;
        unsigned idx = dense ? (xc+yc+zc) : ((xc^yc^zc)&16383u);
        float2 tv = tl[idx];
        float wc = ((c&1)?wx:wx0) * ((c&2)?wy:wy0) * ((c&4)?wz:wz0);
        f0 += wc*tv.x;
        f1 += wc*tv.y;
      }
      bfrag[2*d]   = (__bf16)f0;
      bfrag[2*d+1] = (__bf16)f1;
    }
    MLP_BODY(bfrag, gp)
  }
}

extern "C" void kernel_launch(void* const* d_in, const int* in_sizes, int n_in,
                              void* d_out, int out_size, void* d_ws, size_t ws_size,
                              hipStream_t stream) {
  (void)n_in; (void)out_size;
  const int nB = in_sizes[0] / 3;
  const float* xin = (const float*)d_in[0];
  const float* tab = (const float*)d_in[1];
  const float *w1=(const float*)d_in[2],  *b1=(const float*)d_in[3];
  const float *w2=(const float*)d_in[4],  *b2=(const float*)d_in[5];
  const float *w3=(const float*)d_in[6],  *b3=(const float*)d_in[7];
  const float *cw1=(const float*)d_in[8], *cb1=(const float*)d_in[9];
  const float *cw2=(const float*)d_in[10],*cb2=(const float*)d_in[11];
  const float *cw3=(const float*)d_in[12],*cb3=(const float*)d_in[13];
  const float *cw4=(const float*)d_in[14],*cb4=(const float*)d_in[15];
  float* out = (float*)d_out;

  const size_t need = (size_t)nB * 16u * 4u;   // feat[level][point] packed uint
  if (ws_size >= need){
    dim3 ga((nB + CH - 1) / CH, 16);
    hash_phase<<<ga, dim3(512), 0, stream>>>(xin, tab, (unsigned int*)d_ws, nB);
    const int blocks = (nB + BLOCK - 1) / BLOCK;
    mlp_phase<<<dim3(blocks), dim3(BLOCK), 0, stream>>>(
        (const unsigned int*)d_ws, w1,b1,w2,b2,w3,b3,
        cw1,cb1,cw2,cb2,cw3,cb3,cw4,cb4, out, nB);
  } else {
    const int blocks = (nB + BLOCK - 1) / BLOCK;
    nerf_fused<<<dim3(blocks), dim3(BLOCK), 0, stream>>>(
        xin, tab, w1,b1,w2,b2,w3,b3,
        cw1,cb1,cw2,cb2,cw3,cb3,cw4,cb4, out, nB);
  }
}